// Round 21
// baseline (143.040 us; speedup 1.0000x reference)
//
#include <hip/hip_runtime.h>
#include <stdint.h>

// Pipeline: k_prep (cvt + pack, one dispatch); fused QKV GEMM (256x128, 2-slot dbuf,
// 48KB LDS, 3 blocks/CU); flash attention (MERGED q-block contexts: one KV pass per
// block covers both paired q-blocks -> no duplicate staging; staged KVBLK=128, swapped
// QK^T, in-lane softmax, defer-max, XCD-local grid, native bf16 casts); output GEMM.
// v_cvt_pk_bf16_f32 INLINE ASM BANNED. Direct-from-global K/V BANNED (r15).
// Phased GEMM schedules closed out (r13/r17).
// B=8 TX=TZ=1024 DX=DZ=1024 DATT=DMID=64 H=16 DOUT=1024.

typedef float    f32x4  __attribute__((ext_vector_type(4)));
typedef __bf16   bf16x8 __attribute__((ext_vector_type(8)));
typedef unsigned short u16x4 __attribute__((ext_vector_type(4)));
typedef unsigned short u16x8 __attribute__((ext_vector_type(8)));

#define MASKNEG (-3.0e38f)
#define QSCALE_F (0.125f * 1.4426950408889634f)

__device__ __forceinline__ unsigned short f2bf(float f) {
  unsigned int u = __float_as_uint(f);
  u += 0x7fffu + ((u >> 16) & 1u);   // RNE (software)
  return (unsigned short)(u >> 16);
}

__device__ __forceinline__ unsigned short f2bf_hw(float f) {
  __bf16 h = (__bf16)f;
  return *(unsigned short*)&h;
}

__device__ __forceinline__ void gload16(const void* g, void* s) {
  const __attribute__((address_space(1))) unsigned int* gp =
      (const __attribute__((address_space(1))) unsigned int*)(uintptr_t)g;
  __attribute__((address_space(3))) unsigned int* lp =
      (__attribute__((address_space(3))) unsigned int*)(unsigned int)(uintptr_t)s;
  __builtin_amdgcn_global_load_lds(gp, lp, 16, 0, 0);
}

__device__ __forceinline__ f32x4 mfma16(bf16x8 a, bf16x8 b, f32x4 c) {
  return __builtin_amdgcn_mfma_f32_16x16x32_bf16(a, b, c, 0, 0, 0);
}

// ---------------- fused prep (r20 verbatim) ----------------
__global__ __launch_bounds__(256) void k_prep(const float* __restrict__ x,
                                              const float* __restrict__ z,
                                              unsigned short* __restrict__ out,
                                              const float* __restrict__ Wq,
                                              const float* __restrict__ Wk,
                                              const float* __restrict__ Wv,
                                              const float* __restrict__ Wp,
                                              unsigned short* __restrict__ Oq,
                                              unsigned short* __restrict__ Ok,
                                              unsigned short* __restrict__ Ov,
                                              unsigned short* __restrict__ Op) {
  __shared__ float tile[64][65];
  const int bid = blockIdx.x;
  const int t = threadIdx.x;

  if (bid < 2048) {
    int i = bid * 256 + t;
    const int stride = 2048 * 256;
    for (; i < 2097152; i += stride) {
      const float* in = (i < 1048576) ? (x + (size_t)i * 8) : (z + (size_t)(i - 1048576) * 8);
      const f32x4* p = (const f32x4*)in;
      f32x4 a = p[0], b = p[1];
      u16x8 o;
      o[0] = f2bf(a[0]); o[1] = f2bf(a[1]); o[2] = f2bf(a[2]); o[3] = f2bf(a[3]);
      o[4] = f2bf(b[0]); o[5] = f2bf(b[1]); o[6] = f2bf(b[2]); o[7] = f2bf(b[3]);
      *(u16x8*)(out + (size_t)i * 8) = o;
    }
    return;
  }

  const int pid = bid - 2048;
  const int zid = pid >> 8;
  const int bx = (pid >> 4) & 15;
  const int by = pid & 15;

  if (zid < 3) {
    const float* W = zid == 0 ? Wq : (zid == 1 ? Wk : Wv);
    unsigned short* O = zid == 0 ? Oq : (zid == 1 ? Ok : Ov);
    const int h = bx, d0 = by * 64;
    const int ee = t & 63, r0 = t >> 6;
#pragma unroll
    for (int dd = r0; dd < 64; dd += 4)
      tile[dd][ee] = W[(h * 1024 + d0 + dd) * 64 + ee];
    __syncthreads();
    const int d = t & 63, e0 = t >> 6;
#pragma unroll
    for (int e = e0; e < 64; e += 4)
      O[(h * 64 + e) * 1024 + d0 + d] = f2bf(tile[d][e]);
  } else {
    const int k0 = bx * 64, n0 = by * 64;
    const int nn = t & 63, r0 = t >> 6;
#pragma unroll
    for (int kk = r0; kk < 64; kk += 4)
      tile[kk][nn] = Wp[(k0 + kk) * 1024 + n0 + nn];
    __syncthreads();
    const int kk = t & 63, e0 = t >> 6;
#pragma unroll
    for (int n2 = e0; n2 < 64; n2 += 4)
      Op[(n0 + n2) * 1024 + k0 + kk] = f2bf(tile[kk][n2]);
  }
}

// ---------------- GEMM body (r19/r20 verbatim) ----------------
__device__ __forceinline__ void gemm_body(const unsigned short* __restrict__ A,
                                          const unsigned short* __restrict__ Bt,
                                          const float* __restrict__ bias,
                                          void* __restrict__ outp,
                                          int mode, float oscale,
                                          int brow, int bcol,
                                          unsigned short* As, unsigned short* Bs) {
  const int tid = threadIdx.x;
  const int l = tid & 63, w = tid >> 6;
  const int lrow = l & 15, lk = l >> 4;
  const int wr = (w >> 1) * 128, wc = (w & 1) * 64;

  const int arow = tid >> 2;
  const int asrc = ((tid & 3) ^ ((arow >> 1) & 3)) * 8;
  const unsigned short* ag0 = A + (size_t)(brow + arow) * 1024 + asrc;
  const unsigned short* bg0 = Bt + (size_t)(bcol + arow) * 1024 + asrc;

  int aoff[8], boff[4];
#pragma unroll
  for (int m = 0; m < 8; m++) {
    int row = wr + m * 16 + lrow;
    aoff[m] = row * 64 + ((lk ^ ((row >> 1) & 3)) << 4);
  }
#pragma unroll
  for (int n = 0; n < 4; n++) {
    int col = wc + n * 16 + lrow;
    boff[n] = col * 64 + ((lk ^ ((col >> 1) & 3)) << 4);
  }

  f32x4 acc[8][4];
#pragma unroll
  for (int n = 0; n < 4; n++) {
    float bv = bias[bcol + wc + n * 16 + lrow];
#pragma unroll
    for (int m = 0; m < 8; m++) acc[m][n] = (f32x4){bv, bv, bv, bv};
  }

#define STAGE_G(kt, slot)                                                  \
  {                                                                        \
    char* asb = (char*)As + (slot) * 16384 + w * 1024;                     \
    char* bsb = (char*)Bs + (slot) * 8192 + w * 1024;                      \
    gload16(ag0 + (kt) * 32,          asb);                                \
    gload16(ag0 + (kt) * 32 + 65536,  asb + 4096);                         \
    gload16(ag0 + (kt) * 32 + 131072, asb + 8192);                         \
    gload16(ag0 + (kt) * 32 + 196608, asb + 12288);                        \
    gload16(bg0 + (kt) * 32,          bsb);                                \
    gload16(bg0 + (kt) * 32 + 65536,  bsb + 4096);                         \
  }

  STAGE_G(0, 0)
  asm volatile("s_waitcnt vmcnt(0)" ::: "memory");
  __builtin_amdgcn_s_barrier();
  __builtin_amdgcn_sched_barrier(0);

#pragma unroll 1
  for (int kt = 0; kt < 32; kt++) {
    const int cur = kt & 1;
    if (kt < 31) STAGE_G(kt + 1, cur ^ 1)
    const char* ab = (const char*)As + cur * 16384;
    const char* bb = (const char*)Bs + cur * 8192;
    bf16x8 bfr[4];
#pragma unroll
    for (int n = 0; n < 4; n++) bfr[n] = *(const bf16x8*)(bb + boff[n]);
#pragma unroll
    for (int m = 0; m < 8; m++) {
      bf16x8 af = *(const bf16x8*)(ab + aoff[m]);
#pragma unroll
      for (int n = 0; n < 4; n++)
        acc[m][n] = mfma16(af, bfr[n], acc[m][n]);
    }
    if (kt < 31) {
      asm volatile("s_waitcnt vmcnt(0)" ::: "memory");
      __builtin_amdgcn_s_barrier();
      __builtin_amdgcn_sched_barrier(0);
    }
  }
#undef STAGE_G

  if (mode == 0) {
    unsigned short* C = (unsigned short*)outp;
#pragma unroll
    for (int m = 0; m < 8; m++) {
      int r = brow + wr + m * 16 + 4 * lk;
#pragma unroll
      for (int n = 0; n < 4; n++) {
        int c = bcol + wc + n * 16 + lrow;
        unsigned short* p = C + ((r >> 10) * 16 + (c >> 6)) * 65536 + (r & 1023) * 64 + (c & 63);
#pragma unroll
        for (int j = 0; j < 4; j++) p[j * 64] = f2bf(acc[m][n][j] * oscale);
      }
    }
  } else if (mode == 2) {
    unsigned short* C = (unsigned short*)outp;
#pragma unroll
    for (int m = 0; m < 8; m++) {
      int r = brow + wr + m * 16 + 4 * lk;
#pragma unroll
      for (int n = 0; n < 4; n++) {
        int c = bcol + wc + n * 16 + lrow;
        u16x4 o;
#pragma unroll
        for (int j = 0; j < 4; j++) o[j] = f2bf(acc[m][n][j]);
        *(u16x4*)(C + ((r >> 10) * 16 + (c >> 6)) * 65536 + (c & 63) * 1024 + (r & 1023)) = o;
      }
    }
  } else {
    float* C = (float*)outp;
#pragma unroll
    for (int m = 0; m < 8; m++) {
      int r = brow + wr + m * 16 + 4 * lk;
#pragma unroll
      for (int n = 0; n < 4; n++) {
        int c = bcol + wc + n * 16 + lrow;
#pragma unroll
        for (int j = 0; j < 4; j++) C[(r + j) * 1024 + c] = acc[m][n][j];
      }
    }
  }
}

__global__ __launch_bounds__(256, 3) void k_gemm_qkv(const unsigned short* __restrict__ Xb,
                                                     const unsigned short* __restrict__ Zb,
                                                     const unsigned short* __restrict__ Wqkv,
                                                     const float* __restrict__ bq,
                                                     const float* __restrict__ bk,
                                                     const float* __restrict__ bv,
                                                     unsigned short* __restrict__ Qp,
                                                     unsigned short* __restrict__ Kp,
                                                     unsigned short* __restrict__ Vtp) {
  __shared__ unsigned short As[16384];
  __shared__ unsigned short Bs[8192];
  const int brow = blockIdx.x * 256;
  const int cg = blockIdx.y;
  const int seg = cg >> 3;
  const int bcol = (cg & 7) * 128;
  const unsigned short* A = (seg == 0) ? Xb : Zb;
  const unsigned short* Bt = Wqkv + (size_t)seg * 1048576;
  const float* bias = (seg == 0) ? bq : (seg == 1 ? bk : bv);
  void* outp = (seg == 0) ? (void*)Qp : (seg == 1 ? (void*)Kp : (void*)Vtp);
  const int mode = (seg == 2) ? 2 : 0;
  const float oscale = (seg == 0) ? QSCALE_F : 1.0f;
  gemm_body(A, Bt, bias, outp, mode, oscale, brow, bcol, As, Bs);
}

__global__ __launch_bounds__(256, 3) void k_gemm(const unsigned short* __restrict__ A,
                                                 const unsigned short* __restrict__ Bt,
                                                 const float* __restrict__ bias,
                                                 void* __restrict__ outp,
                                                 int mode, float oscale) {
  __shared__ unsigned short As[16384];
  __shared__ unsigned short Bs[8192];
  gemm_body(A, Bt, bias, outp, mode, oscale, blockIdx.x * 256, blockIdx.y * 128, As, Bs);
}

// ---------------- attn per-tile context body (r20-validated, factored) ----------------
__device__ __forceinline__ void attn_tile(const char* kbase, const char* vbase, char* pw,
                                          int l, int lrow, int lk, int z0, int qw, int qmax,
                                          const bf16x8 (&qf)[2][2], float (&mm)[2],
                                          f32x4 (&lsum)[2], f32x4 (&yacc)[2][4],
                                          bf16x8 ones) {
  if (z0 > qmax) return;

  // S^T: lane holds S[z = z0 + zf*16 + 4*lk + j][q = qw + qn*16 + lrow]
  f32x4 s[2][8];
#pragma unroll
  for (int qn = 0; qn < 2; qn++)
#pragma unroll
    for (int zf = 0; zf < 8; zf++) s[qn][zf] = (f32x4){0.f, 0.f, 0.f, 0.f};
#pragma unroll
  for (int zf = 0; zf < 8; zf++) {
    int zr = zf * 16 + lrow;
#pragma unroll
    for (int kf = 0; kf < 2; kf++) {
      bf16x8 kfr = *(const bf16x8*)(kbase + zr * 128 + (((kf * 4 + lk) ^ (zr & 7)) << 4));
      s[0][zf] = mfma16(kfr, qf[0][kf], s[0][zf]);
      s[1][zf] = mfma16(kfr, qf[1][kf], s[1][zf]);
    }
  }

  if (z0 + 127 > qw) {   // diagonal overlap: mask z > q
#pragma unroll
    for (int qn = 0; qn < 2; qn++) {
      int qg = qw + qn * 16 + lrow;
#pragma unroll
      for (int zf = 0; zf < 8; zf++) {
        int zb = z0 + zf * 16 + 4 * lk;
#pragma unroll
        for (int j = 0; j < 4; j++)
          if (zb + j > qg) s[qn][zf][j] = MASKNEG;
      }
    }
  }

  // in-lane softmax: 31 fmax + 2 shfls; defer-max THR=8 (log2 domain)
#pragma unroll
  for (int qn = 0; qn < 2; qn++) {
    f32x4 r4 = s[qn][0];
#pragma unroll
    for (int zf = 1; zf < 8; zf++)
#pragma unroll
      for (int j = 0; j < 4; j++) r4[j] = fmaxf(r4[j], s[qn][zf][j]);
    float rm = fmaxf(fmaxf(r4[0], r4[1]), fmaxf(r4[2], r4[3]));
    rm = fmaxf(rm, __shfl_xor(rm, 16));
    rm = fmaxf(rm, __shfl_xor(rm, 32));

    if (__any(rm > mm[qn] + 8.f)) {
      float mn = fmaxf(mm[qn], rm);
      float a = __builtin_amdgcn_exp2f(mm[qn] - mn);  // <= 0 arg
      mm[qn] = mn;
      f32x4 av;
#pragma unroll
      for (int j = 0; j < 4; j++)
        av[j] = __shfl(a, (l & 48) | (lk * 4 + j));
      lsum[qn] *= av;
#pragma unroll
      for (int ef = 0; ef < 4; ef++) yacc[qn][ef] *= av;
    }
    float mk = mm[qn];
#pragma unroll
    for (int zf = 0; zf < 8; zf++)
#pragma unroll
      for (int j = 0; j < 4; j++)
        s[qn][zf][j] = __builtin_amdgcn_exp2f(s[qn][zf][j] - mk);  // <= 2^8
  }

  // PV in two 64-z halves
#pragma unroll
  for (int hf = 0; hf < 2; hf++) {
    if (z0 + hf * 64 <= qmax) {
#pragma unroll
      for (int qn = 0; qn < 2; qn++) {
        int q = qn * 16 + lrow;
        char* rowp = pw + q * 128;
#pragma unroll
        for (int zf2 = 0; zf2 < 4; zf2++) {
          int zfg = hf * 4 + zf2;
          u16x4 o;
#pragma unroll
          for (int j = 0; j < 4; j++) o[j] = f2bf_hw(s[qn][zfg][j]);
          int g = zf2 * 2 + (lk >> 1);
          *(u16x4*)(rowp + ((g ^ (q & 7)) << 4) + (lk & 1) * 8) = o;
        }
      }

      asm volatile("s_waitcnt lgkmcnt(0)" ::: "memory");
      __builtin_amdgcn_sched_barrier(0);

      bf16x8 pf[2][2];
#pragma unroll
      for (int qn = 0; qn < 2; qn++)
#pragma unroll
        for (int kf = 0; kf < 2; kf++)
          pf[qn][kf] = *(const bf16x8*)(pw + (qn * 16 + lrow) * 128 + (((kf * 4 + lk) ^ (lrow & 7)) << 4));

#pragma unroll
      for (int qn = 0; qn < 2; qn++)
#pragma unroll
        for (int kf = 0; kf < 2; kf++)
          lsum[qn] = mfma16(pf[qn][kf], ones, lsum[qn]);

#pragma unroll
      for (int ef = 0; ef < 4; ef++) {
        int er = ef * 16 + lrow;
#pragma unroll
        for (int kf = 0; kf < 2; kf++) {
          int g = hf * 8 + kf * 4 + lk;
          bf16x8 vf = *(const bf16x8*)(vbase + er * 256 + ((g ^ (er & 15)) << 4));
          yacc[0][ef] = mfma16(pf[0][kf], vf, yacc[0][ef]);
          yacc[1][ef] = mfma16(pf[1][kf], vf, yacc[1][ef]);
        }
      }
    }
  }
}

// ---------------- flash attention: MERGED contexts, one KV pass per block ----------------
// grid (128, 4): bh = blockIdx.x (XCD-local), pp = blockIdx.y. Contexts: A = qi 7-pp
// (active all tiles), B = qi pp (active t <= pp). One staging pass of nt = 8-pp tiles
// (was 9 with duplicate restaging); compute stays balanced (~9 units/block).
__global__ __launch_bounds__(256, 2) void k_attn(const unsigned short* __restrict__ Qh,
                                                 const unsigned short* __restrict__ Kh,
                                                 const unsigned short* __restrict__ Vth,
                                                 unsigned short* __restrict__ Y) {
  __shared__ unsigned short Ks[16384];
  __shared__ unsigned short Vs[16384];
  __shared__ unsigned short Ps[8192];

  const int tid = threadIdx.x, l = tid & 63, w = tid >> 6;
  const int lrow = l & 15, lk = l >> 4;
  const int bh = blockIdx.x;
  const int pp = blockIdx.y;

  const unsigned short* Qb = Qh + bh * 65536;
  const unsigned short* Kb = Kh + bh * 65536;
  const unsigned short* Vb = Vth + bh * 65536;

  bf16x8 ones;
#pragma unroll
  for (int j = 0; j < 8; j++) ones[j] = (__bf16)1.0f;

  const int krl = l >> 3;
  const int kgp = l & 7;
  const unsigned short* kgsrc = Kb + (w * 32 + krl) * 64 + ((kgp ^ krl) * 8);
  const int vrl = l >> 4;
  const int vgp = l & 15;
  const int vr0 = w * 16 + 0 * 4 + vrl;
  const int vr1 = w * 16 + 1 * 4 + vrl;
  const int vr2 = w * 16 + 2 * 4 + vrl;
  const int vr3 = w * 16 + 3 * 4 + vrl;
  const int voff0 = vr0 * 1024 + ((vgp ^ (vr0 & 15)) * 8);
  const int voff1 = vr1 * 1024 + ((vgp ^ (vr1 & 15)) * 8);
  const int voff2 = vr2 * 1024 + ((vgp ^ (vr2 & 15)) * 8);
  const int voff3 = vr3 * 1024 + ((vgp ^ (vr3 & 15)) * 8);

  char* pw = (char*)Ps + w * 4096;

  const int b = bh >> 4, h = bh & 15;

  // context A: qi = 7-pp ; context B: qi = pp
  const int qwA = (7 - pp) * 128 + w * 32, qmaxA = qwA + 31;
  const int qwB = pp * 128 + w * 32,       qmaxB = qwB + 31;

  bf16x8 qfA[2][2], qfB[2][2];
#pragma unroll
  for (int qn = 0; qn < 2; qn++) {
    const unsigned short* qpA = Qb + (qwA + qn * 16 + lrow) * 64 + lk * 8;
    qfA[qn][0] = *(const bf16x8*)qpA;
    qfA[qn][1] = *(const bf16x8*)(qpA + 32);
    const unsigned short* qpB = Qb + (qwB + qn * 16 + lrow) * 64 + lk * 8;
    qfB[qn][0] = *(const bf16x8*)qpB;
    qfB[qn][1] = *(const bf16x8*)(qpB + 32);
  }

  float mmA[2], mmB[2];
  f32x4 lsumA[2], lsumB[2], yaccA[2][4], yaccB[2][4];
#pragma unroll
  for (int qn = 0; qn < 2; qn++) {
    mmA[qn] = MASKNEG; mmB[qn] = MASKNEG;
    lsumA[qn] = (f32x4){0.f, 0.f, 0.f, 0.f};
    lsumB[qn] = (f32x4){0.f, 0.f, 0.f, 0.f};
#pragma unroll
    for (int ef = 0; ef < 4; ef++) {
      yaccA[qn][ef] = (f32x4){0.f, 0.f, 0.f, 0.f};
      yaccB[qn][ef] = (f32x4){0.f, 0.f, 0.f, 0.f};
    }
  }

  const int nt = 8 - pp;   // tiles of 128 z (covers context A fully; B needs t <= pp)

  // prologue: stage tile 0 into buffer 0
  {
    char* kb = (char*)Ks + w * 4096;
    char* vb2 = (char*)Vs + w * 4096;
    gload16(kgsrc + 0,    kb);
    gload16(kgsrc + 512,  kb + 1024);
    gload16(kgsrc + 1024, kb + 2048);
    gload16(kgsrc + 1536, kb + 3072);
    gload16(Vb + voff0, vb2);
    gload16(Vb + voff1, vb2 + 1024);
    gload16(Vb + voff2, vb2 + 2048);
    gload16(Vb + voff3, vb2 + 3072);
  }
  __syncthreads();

#pragma unroll 1
  for (int t = 0; t < nt; t++) {
    const int z0 = t * 128;
    const int cur = t & 1;
    if (t < nt - 1) {
      const int zn = (t + 1) * 128;
      char* kb = (char*)Ks + (cur ^ 1) * 16384 + w * 4096;
      char* vb2 = (char*)Vs + (cur ^ 1) * 16384 + w * 4096;
      const unsigned short* kgt = kgsrc + zn * 64;
      gload16(kgt + 0,    kb);
      gload16(kgt + 512,  kb + 1024);
      gload16(kgt + 1024, kb + 2048);
      gload16(kgt + 1536, kb + 3072);
      gload16(Vb + voff0 + zn, vb2);
      gload16(Vb + voff1 + zn, vb2 + 1024);
      gload16(Vb + voff2 + zn, vb2 + 2048);
      gload16(Vb + voff3 + zn, vb2 + 3072);
    }

    const char* kbase = (const char*)Ks + cur * 16384;
    const char* vbase = (const char*)Vs + cur * 16384;

    attn_tile(kbase, vbase, pw, l, lrow, lk, z0, qwA, qmaxA, qfA, mmA, lsumA, yaccA, ones);
    attn_tile(kbase, vbase, pw, l, lrow, lk, z0, qwB, qmaxB, qfB, mmB, lsumB, yaccB, ones);

    __syncthreads();
  }

  // epilogues: q = qw + qn*16 + lk*4 + j, e = ef*16 + lrow
#pragma unroll
  for (int qn = 0; qn < 2; qn++) {
    f32x4 rinv;
#pragma unroll
    for (int j = 0; j < 4; j++) rinv[j] = 1.0f / lsumA[qn][j];
#pragma unroll
    for (int ef = 0; ef < 4; ef++) {
      int col = h * 64 + ef * 16 + lrow;
#pragma unroll
      for (int j = 0; j < 4; j++) {
        int xq = qwA + qn * 16 + lk * 4 + j;
        Y[(b * 1024 + xq) * 1024 + col] = f2bf_hw(yaccA[qn][ef][j] * rinv[j]);
      }
    }
  }
#pragma unroll
  for (int qn = 0; qn < 2; qn++) {
    f32x4 rinv;
#pragma unroll
    for (int j = 0; j < 4; j++) rinv[j] = 1.0f / lsumB[qn][j];
#pragma unroll
    for (int ef = 0; ef < 4; ef++) {
      int col = h * 64 + ef * 16 + lrow;
#pragma unroll
      for (int j = 0; j < 4; j++) {
        int xq = qwB + qn * 16 + lk * 4 + j;
        Y[(b * 1024 + xq) * 1024 + col] = f2bf_hw(yaccB[qn][ef][j] * rinv[j]);
      }
    }
  }
}

// ---------------- launch ----------------
extern "C" void kernel_launch(void* const* d_in, const int* in_sizes, int n_in,
                              void* d_out, int out_size, void* d_ws, size_t ws_size,
                              hipStream_t stream) {
  const float* x  = (const float*)d_in[0];
  const float* z  = (const float*)d_in[1];
  const float* Wq = (const float*)d_in[2];
  const float* bq = (const float*)d_in[3];
  const float* Wk = (const float*)d_in[4];
  const float* bk = (const float*)d_in[5];
  const float* Wv = (const float*)d_in[6];
  const float* bv = (const float*)d_in[7];
  const float* Wp = (const float*)d_in[8];
  const float* bp = (const float*)d_in[9];
  (void)in_sizes; (void)n_in; (void)out_size; (void)ws_size;

  char* ws = (char*)d_ws;
  unsigned short* Xb  = (unsigned short*)(ws + 0);
  unsigned short* Zb  = (unsigned short*)(ws + 16777216);
  unsigned short* Wqt = (unsigned short*)(ws + 33554432);  // Wqt/Wkt/Wvt contiguous = Wqkv
  unsigned short* Wkt = (unsigned short*)(ws + 35651584);
  unsigned short* Wvt = (unsigned short*)(ws + 37748736);
  unsigned short* Wpt = (unsigned short*)(ws + 39845888);
  unsigned short* Qp  = (unsigned short*)(ws + 41943040);
  unsigned short* Kp  = (unsigned short*)(ws + 58720256);
  unsigned short* Vtp = (unsigned short*)(ws + 75497472);

  k_prep<<<dim3(3072), dim3(256), 0, stream>>>(x, z, Xb, Wq, Wk, Wv, Wp, Wqt, Wkt, Wvt, Wpt);

  k_gemm_qkv<<<dim3(32, 24), dim3(256), 0, stream>>>(Xb, Zb, Wqt, bq, bk, bv, Qp, Kp, Vtp);

  k_attn<<<dim3(128, 4), dim3(256), 0, stream>>>(Qp, Kp, Vtp, Xb /*Y*/);

  k_gemm<<<dim3(32, 8), dim3(256), 0, stream>>>(Xb, Wpt, bp, d_out, 3, 1.0f);
}